// Round 11
// baseline (506.242 us; speedup 1.0000x reference)
//
#include <hip/hip_runtime.h>
#include <stdint.h>

#define NV 6890
#define NJ 24
#define NB_ 256
#define NP 100
#define MP 6912          // GEMM M padded to 108*64
#define MAGIC 0x13579BDF

// out element offsets (fp32)
#define OUT_JT   5291520
#define OUT_PLN  5309952

// workspace float offsets
#define O_JP 0           // 24*8*3 = 576 J_shaped partials
#define O_A  576         // 256*24*12 = 73728 fp32 joint transforms
#define O_PW 74304       // 400*24 = 9600 pre-gathered plane weights
#define O_FL 83904       // 192 int flags (ends 84096)
// workspace u16 offsets
#define O_WT 169984      // W~ bf16 [MP][96] (byte 339968 = float 84992 > 84096 OK)
#define O_AT 833536      // A~ bf16 [768][96]

typedef unsigned short u16;
typedef unsigned int u32;
typedef __attribute__((ext_vector_type(8))) short bf16x8;
typedef __attribute__((ext_vector_type(4))) float f32x4;

__device__ __forceinline__ u16 f2bf(float f) {
    u32 u = __float_as_uint(f);
    u += 0x7FFFu + ((u >> 16) & 1u);   // RNE
    return (u16)(u >> 16);
}

__constant__ int c_par[24] = {-1,0,0,0,1,2,3,4,5,6,7,8,9,9,9,12,13,14,16,17,18,19,20,21};

struct Params {
    const float *vt, *sd, *jreg, *lw, *betas, *bpwf, *rback, *rfront,
                *lback, *lfront, *transl, *gor, *ip_bl, *ip_fl, *ip_br, *ip_fr;
    const int *ids_bl, *ids_fl, *ids_br, *ids_fr;
    float* ws;
    u16* wsu;
    float* out;
};

// ========== D1: W~ build + J-partials + (chain + pregather) ==========
// blocks 0..26   : W~ build (independent)
// blocks 27..218 : J_shaped partials -> threadfence + MAGIC flag (release)
// blocks 219..474: pregather; lane 0 ONLY sweeps the 192 flags with s_sleep(64)
//                  backoff (256 pollers total -- R10's 49k-thread spin starved
//                  producers via agent-acquire cache invalidations); then chain.
// Grid 475 <= 512 co-resident (launch_bounds(256,2), VGPR 60, LDS 3KB) -> safe.
__global__ __launch_bounds__(256, 2) void k_dA(Params P) {
    int bx = blockIdx.x, tid = threadIdx.x;
    if (bx < 27) {
        // ---- W~: one vertex/thread, vs computed inline ----
        int v = bx * 256 + tid;                 // < 6912
        u16 buf[96];
        if (v < NV) {
            float be[11];
#pragma unroll
            for (int l = 0; l < 11; ++l) be[l] = P.betas[l];
            const float* sr = P.sd + (size_t)v * 30;
            const float* vr = P.vt + (size_t)v * 3;
            float vs[3];
#pragma unroll
            for (int n = 0; n < 3; ++n) {
                float acc = vr[n];
#pragma unroll
                for (int l = 0; l < 10; ++l) acc += be[1 + l] * sr[n * 10 + l];
                vs[n] = acc * be[0];
            }
            const float* wr = P.lw + (size_t)v * 24;
#pragma unroll
            for (int j = 0; j < 24; ++j) {
                float w = wr[j];
                buf[j*4+0] = f2bf(w * vs[0]);
                buf[j*4+1] = f2bf(w * vs[1]);
                buf[j*4+2] = f2bf(w * vs[2]);
                buf[j*4+3] = f2bf(w);
            }
        } else {
#pragma unroll
            for (int m = 0; m < 96; ++m) buf[m] = 0;
        }
        uint4* dst = (uint4*)(P.wsu + O_WT + (size_t)v * 96);
        const uint4* src = (const uint4*)buf;
#pragma unroll
        for (int m = 0; m < 12; ++m) dst[m] = src[m];
        return;
    }
    if (bx < 219) {
        // ---- J_shaped partial (j, slice) ----
        int idx = bx - 27;                      // < 192
        int j = idx >> 3, sl = idx & 7;
        int i0 = sl * 862, i1 = (i0 + 862 < NV) ? i0 + 862 : NV;
        float b0 = P.betas[0];
        float be[10];
#pragma unroll
        for (int l = 0; l < 10; ++l) be[l] = P.betas[1 + l];
        float s0 = 0.f, s1 = 0.f, s2 = 0.f;
        for (int i = i0 + tid; i < i1; i += 256) {
            float w = P.jreg[(size_t)j * NV + i];
            const float* sr = P.sd + (size_t)i * 30;
            const float* vr = P.vt + (size_t)i * 3;
            float c0 = vr[0], c1 = vr[1], c2 = vr[2];
#pragma unroll
            for (int l = 0; l < 10; ++l) {
                c0 += be[l] * sr[l];
                c1 += be[l] * sr[10 + l];
                c2 += be[l] * sr[20 + l];
            }
            s0 += w * (c0 * b0); s1 += w * (c1 * b0); s2 += w * (c2 * b0);
        }
        __shared__ float r0[256], r1[256], r2[256];
        r0[tid] = s0; r1[tid] = s1; r2[tid] = s2;
        __syncthreads();
        for (int off = 128; off > 0; off >>= 1) {
            if (tid < off) { r0[tid] += r0[tid+off]; r1[tid] += r1[tid+off]; r2[tid] += r2[tid+off]; }
            __syncthreads();
        }
        if (tid == 0) {
            P.ws[O_JP + idx*3 + 0] = r0[0];
            P.ws[O_JP + idx*3 + 1] = r1[0];
            P.ws[O_JP + idx*3 + 2] = r2[0];
            __threadfence();
            __hip_atomic_store((int*)P.ws + O_FL + idx, MAGIC,
                               __ATOMIC_RELEASE, __HIP_MEMORY_SCOPE_AGENT);
        }
        return;
    }
    // ---- chain block for batch b, plus pregather slice ----
    int b = bx - 219;
    if (tid < 38) {
        int q = b * 38 + tid;
        if (q < 9600) {
            int rr = q / 24, j = q - 24 * rr;   // rr = plane*100+p
            int plane = rr / 100, p = rr - 100 * plane;
            const int* ids = (plane == 0) ? P.ids_bl : (plane == 1) ? P.ids_fl
                           : (plane == 2) ? P.ids_br : P.ids_fr;
            P.ws[O_PW + q] = P.lw[(size_t)ids[p] * 24 + j];
        }
    }
    // single-lane flag sweep (low-contention)
    if (tid == 0) {
        const int* fl = (const int*)P.ws + O_FL;
        for (int k = 0; k < 192; ++k) {
            while (__hip_atomic_load(fl + k, __ATOMIC_ACQUIRE,
                                     __HIP_MEMORY_SCOPE_AGENT) != MAGIC) {
                __builtin_amdgcn_s_sleep(64);
            }
        }
    }
    __syncthreads();
    __shared__ float js[72];
    __shared__ float sT[24][12];
    __shared__ float sJ[24][3];
    if (tid < 72) {
        int j = tid / 3, cc = tid - 3 * j;
        float a = 0.f;
#pragma unroll
        for (int s = 0; s < 8; ++s)
            a += __hip_atomic_load(P.ws + O_JP + (j*8 + s)*3 + cc,
                                   __ATOMIC_RELAXED, __HIP_MEMORY_SCOPE_AGENT);
        js[tid] = a;
    }
    __syncthreads();
    int j = tid;
    if (j < 24) {
        float px, py, pz;
        const float* bp = P.bpwf;
        if (j == 0)      { px = P.gor[b*3];   py = P.gor[b*3+1];   pz = P.gor[b*3+2]; }
        else if (j <= 6) { int o = b*57 + 3*(j-1); px = bp[o]; py = bp[o+1]; pz = bp[o+2]; }
        else if (j == 7) { px = P.lback[b*3]; py = P.lback[b*3+1]; pz = P.lback[b*3+2]; }
        else if (j == 8) { px = P.rback[b*3]; py = P.rback[b*3+1]; pz = P.rback[b*3+2]; }
        else if (j == 9) { int o = b*57 + 18;     px = bp[o]; py = bp[o+1]; pz = bp[o+2]; }
        else if (j == 10){ px = P.lfront[b];  py = 0.f; pz = 0.f; }
        else if (j == 11){ px = P.rfront[b];  py = 0.f; pz = 0.f; }
        else             { int o = b*57 + 21 + 3*(j-12); px = bp[o]; py = bp[o+1]; pz = bp[o+2]; }
        float ax = px + 1e-8f, ay = py + 1e-8f, az = pz + 1e-8f;
        float ang = sqrtf(ax*ax + ay*ay + az*az);
        float inv = 1.0f / ang;
        float dx = px * inv, dy = py * inv, dz = pz * inv;
        float c = cosf(ang), s = sinf(ang), t = 1.0f - c;
        sJ[j][0] = js[j*3]; sJ[j][1] = js[j*3+1]; sJ[j][2] = js[j*3+2];
        int p = c_par[j];
        float rx = sJ[j][0], ry = sJ[j][1], rz = sJ[j][2];
        if (p >= 0) { rx -= js[p*3]; ry -= js[p*3+1]; rz -= js[p*3+2]; }
        sT[j][0] = 1.f - t*(dy*dy + dz*dz);
        sT[j][1] = -s*dz + t*dx*dy;
        sT[j][2] =  s*dy + t*dx*dz;
        sT[j][3] = rx;
        sT[j][4] =  s*dz + t*dx*dy;
        sT[j][5] = 1.f - t*(dx*dx + dz*dz);
        sT[j][6] = -s*dx + t*dy*dz;
        sT[j][7] = ry;
        sT[j][8] = -s*dy + t*dx*dz;
        sT[j][9] =  s*dx + t*dy*dz;
        sT[j][10]= 1.f - t*(dx*dx + dy*dy);
        sT[j][11]= rz;
    }
    __syncthreads();
    if (j < 24) {
        int path[12]; int d = 0; int cur = j;
        while (cur >= 0) { path[d++] = cur; cur = c_par[cur]; }
        float g[12];
        int r = path[d - 1];
#pragma unroll
        for (int m = 0; m < 12; ++m) g[m] = sT[r][m];
        for (int i = d - 2; i >= 0; --i) {
            int n = path[i];
            float h[12];
#pragma unroll
            for (int row = 0; row < 3; ++row) {
                float a0 = g[row*4+0], a1 = g[row*4+1], a2 = g[row*4+2], a3 = g[row*4+3];
                h[row*4+0] = a0*sT[n][0] + a1*sT[n][4] + a2*sT[n][8];
                h[row*4+1] = a0*sT[n][1] + a1*sT[n][5] + a2*sT[n][9];
                h[row*4+2] = a0*sT[n][2] + a1*sT[n][6] + a2*sT[n][10];
                h[row*4+3] = a0*sT[n][3] + a1*sT[n][7] + a2*sT[n][11] + a3;
            }
#pragma unroll
            for (int m = 0; m < 12; ++m) g[m] = h[m];
        }
        size_t jo = (size_t)OUT_JT + ((size_t)b * 24 + j) * 3;
        P.out[jo+0] = g[3]; P.out[jo+1] = g[7]; P.out[jo+2] = g[11];
        float jx = sJ[j][0], jy = sJ[j][1], jz = sJ[j][2];
        float Av[12];
        Av[0]=g[0]; Av[1]=g[1]; Av[2]=g[2];   Av[3] = g[3]  - (g[0]*jx + g[1]*jy + g[2]*jz);
        Av[4]=g[4]; Av[5]=g[5]; Av[6]=g[6];   Av[7] = g[7]  - (g[4]*jx + g[5]*jy + g[6]*jz);
        Av[8]=g[8]; Av[9]=g[9]; Av[10]=g[10]; Av[11]= g[11] - (g[8]*jx + g[9]*jy + g[10]*jz);
        float* Ab = P.ws + O_A + ((size_t)b * 24 + j) * 12;
#pragma unroll
        for (int m = 0; m < 12; ++m) Ab[m] = Av[m];
        u16* at = P.wsu + O_AT;
#pragma unroll
        for (int m = 0; m < 3; ++m)
#pragma unroll
            for (int n = 0; n < 4; ++n)
                at[(size_t)(b*3 + m) * 96 + j*4 + n] = f2bf(Av[m*4 + n]);
    }
}

// ========== D2: MFMA GEMM (verts) + foot planes (R9-proven) ==========
__global__ __launch_bounds__(256) void k_d3(Params P) {
    if (blockIdx.y < 12) {
        __shared__ float ltile[64][66];
        const u16* wt = P.wsu + O_WT;
        const u16* at = P.wsu + O_AT;
        int tid = threadIdx.x;
        int lane = tid & 63;
        int wave = tid >> 6;
        int row_in = lane & 15, quad = lane >> 4;
        int v0 = blockIdx.x * 64 + wave * 16;
        int c0 = blockIdx.y * 64;

        f32x4 acc0 = {0.f,0.f,0.f,0.f}, acc1 = acc0, acc2 = acc0, acc3 = acc0;
#pragma unroll
        for (int kc = 0; kc < 96; kc += 32) {
            bf16x8 a  = *(const bf16x8*)(wt + (size_t)(v0 + row_in) * 96 + kc + quad * 8);
            bf16x8 b0 = *(const bf16x8*)(at + (size_t)(c0 +  0 + row_in) * 96 + kc + quad * 8);
            bf16x8 b1 = *(const bf16x8*)(at + (size_t)(c0 + 16 + row_in) * 96 + kc + quad * 8);
            bf16x8 b2 = *(const bf16x8*)(at + (size_t)(c0 + 32 + row_in) * 96 + kc + quad * 8);
            bf16x8 b3 = *(const bf16x8*)(at + (size_t)(c0 + 48 + row_in) * 96 + kc + quad * 8);
            acc0 = __builtin_amdgcn_mfma_f32_16x16x32_bf16(a, b0, acc0, 0, 0, 0);
            acc1 = __builtin_amdgcn_mfma_f32_16x16x32_bf16(a, b1, acc1, 0, 0, 0);
            acc2 = __builtin_amdgcn_mfma_f32_16x16x32_bf16(a, b2, acc2, 0, 0, 0);
            acc3 = __builtin_amdgcn_mfma_f32_16x16x32_bf16(a, b3, acc3, 0, 0, 0);
        }
        int vbase = wave * 16 + quad * 4;
#pragma unroll
        for (int s = 0; s < 4; ++s) {
            f32x4 acc = (s == 0) ? acc0 : (s == 1) ? acc1 : (s == 2) ? acc2 : acc3;
#pragma unroll
            for (int r = 0; r < 4; ++r)
                ltile[vbase + r][s * 16 + row_in] = acc[r];
        }
        __syncthreads();
        int vblk = blockIdx.x * 64;
        int bstart = c0 / 3;
        int bend = (c0 + 63) / 3;
        for (int b = bstart; b <= bend; ++b) {
            if (tid < 192) {
                int vl = tid / 3, m = tid - 3 * (tid / 3);
                int cl = b * 3 + m - c0;
                int v = vblk + vl;
                if (cl >= 0 && cl < 64 && v < NV)
                    P.out[((size_t)b * NV + v) * 3 + m] = ltile[vl][cl] + P.transl[b * 3 + m];
            }
        }
        return;
    }
    // ---- planes ----
    for (int idx = blockIdx.x * 256 + threadIdx.x; idx < NB_ * 400; idx += 108 * 256) {
        int b = idx / 400;
        int rr = idx - 400 * b;              // plane*100 + p
        const float* w  = P.ws + O_PW + rr * 24;
        const float* Ab = P.ws + O_A + (size_t)b * 288;
        float T[12];
#pragma unroll
        for (int m = 0; m < 12; ++m) T[m] = 0.f;
#pragma unroll
        for (int j = 0; j < NJ; ++j) {
            float wj = w[j];
#pragma unroll
            for (int m = 0; m < 12; ++m) T[m] += wj * Ab[j * 12 + m];
        }
        int plane = rr / 100, p = rr - 100 * plane;
        const float* ip = (plane == 0) ? P.ip_bl : (plane == 1) ? P.ip_fl
                        : (plane == 2) ? P.ip_br : P.ip_fr;
        size_t io = ((size_t)b * NP + p) * 3;
        float vx = ip[io+0], vy = ip[io+1], vz = ip[io+2];
        float ox = T[0]*vx + T[1]*vy + T[2]*vz  + T[3]  + P.transl[b*3+0];
        float oy = T[4]*vx + T[5]*vy + T[6]*vz  + T[7]  + P.transl[b*3+1];
        float oz = T[8]*vx + T[9]*vy + T[10]*vz + T[11] + P.transl[b*3+2];
        size_t o = (size_t)OUT_PLN + (size_t)idx * 3;
        P.out[o+0] = ox; P.out[o+1] = oy; P.out[o+2] = oz;
    }
}

extern "C" void kernel_launch(void* const* d_in, const int* in_sizes, int n_in,
                              void* d_out, int out_size, void* d_ws, size_t ws_size,
                              hipStream_t stream) {
    Params P;
    P.vt     = (const float*)d_in[0];
    P.sd     = (const float*)d_in[1];
    P.jreg   = (const float*)d_in[2];
    P.lw     = (const float*)d_in[3];
    P.betas  = (const float*)d_in[4];
    P.bpwf   = (const float*)d_in[5];
    P.rback  = (const float*)d_in[6];
    P.rfront = (const float*)d_in[7];
    P.lback  = (const float*)d_in[8];
    P.lfront = (const float*)d_in[9];
    P.transl = (const float*)d_in[10];
    P.gor    = (const float*)d_in[11];
    P.ip_bl  = (const float*)d_in[12];
    P.ip_fl  = (const float*)d_in[13];
    P.ip_br  = (const float*)d_in[14];
    P.ip_fr  = (const float*)d_in[15];
    // d_in[16] = parents (hardcoded)
    P.ids_bl = (const int*)d_in[17];
    P.ids_br = (const int*)d_in[18];
    P.ids_fl = (const int*)d_in[19];
    P.ids_fr = (const int*)d_in[20];
    P.ws  = (float*)d_ws;
    P.wsu = (u16*)d_ws;
    P.out = (float*)d_out;

    k_dA<<<dim3(475), 256, 0, stream>>>(P);
    k_d3<<<dim3(108, 13), 256, 0, stream>>>(P);
}

// Round 13
// 208.785 us; speedup vs baseline: 2.4247x; 2.4247x over previous
//
#include <hip/hip_runtime.h>
#include <stdint.h>

#define NV 6890
#define NJ 24
#define NB_ 256
#define NP 100
#define MP 6912          // GEMM M padded to 108*64
#define MAGIC 0x13579BDF
#define NSL 2            // slices per joint for J partials
#define NFL (NJ * NSL)   // 48 flags

// out element offsets (fp32)
#define OUT_JT   5291520
#define OUT_PLN  5309952

// workspace float offsets
#define O_JP 0           // 48*3 J_shaped partials
#define O_A  576         // 256*24*12 = 73728 fp32 joint transforms
#define O_PW 74304       // 400*24 = 9600 pre-gathered plane weights
#define O_FL 83904       // 48 int flags
// workspace u16 offsets
#define O_WT 169984      // W~ bf16 [MP][96] (float off 84992 — clear of O_FL)
#define O_AT 833536      // A~ bf16 [768][96]

typedef unsigned short u16;
typedef unsigned int u32;
typedef __attribute__((ext_vector_type(8))) short bf16x8;
typedef __attribute__((ext_vector_type(4))) float f32x4;

__device__ __forceinline__ u16 f2bf(float f) {
    u32 u = __float_as_uint(f);
    u += 0x7FFFu + ((u >> 16) & 1u);   // RNE
    return (u16)(u >> 16);
}

__constant__ int c_par[24] = {-1,0,0,0,1,2,3,4,5,6,7,8,9,9,9,12,13,14,16,17,18,19,20,21};

struct Params {
    const float *vt, *sd, *jreg, *lw, *betas, *bpwf, *rback, *rfront,
                *lback, *lfront, *transl, *gor, *ip_bl, *ip_fl, *ip_br, *ip_fr;
    const int *ids_bl, *ids_fl, *ids_br, *ids_fr;
    float* ws;
    u16* wsu;
    float* out;
};

// ========== D1: W~ build + J-partials + (chain + pregather) ==========
// blocks 0..26  : W~ build (independent)
// blocks 27..74 : J_shaped partials (24 j x 2 slices) -> fence + MAGIC release
// blocks 75..330: pregather; 48 lanes poll flags IN PARALLEL after a dummy
//                 acquire (gfx9 acquire invalidates AFTER the load -- the dummy
//                 eats the stale poison line so the first real check is fresh;
//                 R11's sequential sweep paid one 1.7us sleep per flag = 330us).
// Grid 331 <= 512 co-resident (launch_bounds(256,2)) -> spin cannot deadlock.
__global__ __launch_bounds__(256, 2) void k_dA(Params P) {
    int bx = blockIdx.x, tid = threadIdx.x;
    if (bx < 27) {
        // ---- W~: one vertex/thread, vs computed inline ----
        int v = bx * 256 + tid;                 // < 6912
        u16 buf[96];
        if (v < NV) {
            float be[11];
#pragma unroll
            for (int l = 0; l < 11; ++l) be[l] = P.betas[l];
            const float* sr = P.sd + (size_t)v * 30;
            const float* vr = P.vt + (size_t)v * 3;
            float vs[3];
#pragma unroll
            for (int n = 0; n < 3; ++n) {
                float acc = vr[n];
#pragma unroll
                for (int l = 0; l < 10; ++l) acc += be[1 + l] * sr[n * 10 + l];
                vs[n] = acc * be[0];
            }
            const float* wr = P.lw + (size_t)v * 24;
#pragma unroll
            for (int j = 0; j < 24; ++j) {
                float w = wr[j];
                buf[j*4+0] = f2bf(w * vs[0]);
                buf[j*4+1] = f2bf(w * vs[1]);
                buf[j*4+2] = f2bf(w * vs[2]);
                buf[j*4+3] = f2bf(w);
            }
        } else {
#pragma unroll
            for (int m = 0; m < 96; ++m) buf[m] = 0;
        }
        uint4* dst = (uint4*)(P.wsu + O_WT + (size_t)v * 96);
        const uint4* src = (const uint4*)buf;
#pragma unroll
        for (int m = 0; m < 12; ++m) dst[m] = src[m];
        return;
    }
    if (bx < 27 + NFL) {
        // ---- J_shaped partial (j, slice): ~3445 vertices ----
        int idx = bx - 27;                      // < 48
        int j = idx >> 1, sl = idx & 1;
        int i0 = sl * 3445, i1 = (i0 + 3445 < NV) ? i0 + 3445 : NV;
        float b0 = P.betas[0];
        float be[10];
#pragma unroll
        for (int l = 0; l < 10; ++l) be[l] = P.betas[1 + l];
        float s0 = 0.f, s1 = 0.f, s2 = 0.f;
        for (int i = i0 + tid; i < i1; i += 256) {
            float w = P.jreg[(size_t)j * NV + i];
            const float* sr = P.sd + (size_t)i * 30;
            const float* vr = P.vt + (size_t)i * 3;
            float c0 = vr[0], c1 = vr[1], c2 = vr[2];
#pragma unroll
            for (int l = 0; l < 10; ++l) {
                c0 += be[l] * sr[l];
                c1 += be[l] * sr[10 + l];
                c2 += be[l] * sr[20 + l];
            }
            s0 += w * (c0 * b0); s1 += w * (c1 * b0); s2 += w * (c2 * b0);
        }
        __shared__ float r0[256], r1[256], r2[256];
        r0[tid] = s0; r1[tid] = s1; r2[tid] = s2;
        __syncthreads();
        for (int off = 128; off > 0; off >>= 1) {
            if (tid < off) { r0[tid] += r0[tid+off]; r1[tid] += r1[tid+off]; r2[tid] += r2[tid+off]; }
            __syncthreads();
        }
        if (tid == 0) {
            P.ws[O_JP + idx*3 + 0] = r0[0];
            P.ws[O_JP + idx*3 + 1] = r1[0];
            P.ws[O_JP + idx*3 + 2] = r2[0];
            __threadfence();
            __hip_atomic_store((int*)P.ws + O_FL + idx, MAGIC,
                               __ATOMIC_RELEASE, __HIP_MEMORY_SCOPE_AGENT);
        }
        return;
    }
    // ---- chain block for batch b, plus pregather slice ----
    int b = bx - (27 + NFL);
    if (tid < 38) {
        int q = b * 38 + tid;
        if (q < 9600) {
            int rr = q / 24, j = q - 24 * rr;   // rr = plane*100+p
            int plane = rr / 100, p = rr - 100 * plane;
            const int* ids = (plane == 0) ? P.ids_bl : (plane == 1) ? P.ids_fl
                           : (plane == 2) ? P.ids_br : P.ids_fr;
            P.ws[O_PW + q] = P.lw[(size_t)ids[p] * 24 + j];
        }
    }
    // parallel flag poll: dummy acquire invalidates stale line, then check
    if (tid < NFL) {
        const int* fl = (const int*)P.ws + O_FL;
        (void)__hip_atomic_load(fl + tid, __ATOMIC_ACQUIRE,
                                __HIP_MEMORY_SCOPE_AGENT);   // eat stale value
        while (__hip_atomic_load(fl + tid, __ATOMIC_ACQUIRE,
                                 __HIP_MEMORY_SCOPE_AGENT) != MAGIC) {
            __builtin_amdgcn_s_sleep(8);    // ~512 cyc cadence (const imm only)
        }
    }
    __syncthreads();
    __shared__ float js[72];
    __shared__ float sT[24][12];
    __shared__ float sJ[24][3];
    if (tid < 72) {
        int j = tid / 3, cc = tid - 3 * j;
        float a = 0.f;
#pragma unroll
        for (int s = 0; s < NSL; ++s)
            a += __hip_atomic_load(P.ws + O_JP + (j*NSL + s)*3 + cc,
                                   __ATOMIC_RELAXED, __HIP_MEMORY_SCOPE_AGENT);
        js[tid] = a;
    }
    __syncthreads();
    int j = tid;
    if (j < 24) {
        float px, py, pz;
        const float* bp = P.bpwf;
        if (j == 0)      { px = P.gor[b*3];   py = P.gor[b*3+1];   pz = P.gor[b*3+2]; }
        else if (j <= 6) { int o = b*57 + 3*(j-1); px = bp[o]; py = bp[o+1]; pz = bp[o+2]; }
        else if (j == 7) { px = P.lback[b*3]; py = P.lback[b*3+1]; pz = P.lback[b*3+2]; }
        else if (j == 8) { px = P.rback[b*3]; py = P.rback[b*3+1]; pz = P.rback[b*3+2]; }
        else if (j == 9) { int o = b*57 + 18;     px = bp[o]; py = bp[o+1]; pz = bp[o+2]; }
        else if (j == 10){ px = P.lfront[b];  py = 0.f; pz = 0.f; }
        else if (j == 11){ px = P.rfront[b];  py = 0.f; pz = 0.f; }
        else             { int o = b*57 + 21 + 3*(j-12); px = bp[o]; py = bp[o+1]; pz = bp[o+2]; }
        float ax = px + 1e-8f, ay = py + 1e-8f, az = pz + 1e-8f;
        float ang = sqrtf(ax*ax + ay*ay + az*az);
        float inv = 1.0f / ang;
        float dx = px * inv, dy = py * inv, dz = pz * inv;
        float c = cosf(ang), s = sinf(ang), t = 1.0f - c;
        sJ[j][0] = js[j*3]; sJ[j][1] = js[j*3+1]; sJ[j][2] = js[j*3+2];
        int p = c_par[j];
        float rx = sJ[j][0], ry = sJ[j][1], rz = sJ[j][2];
        if (p >= 0) { rx -= js[p*3]; ry -= js[p*3+1]; rz -= js[p*3+2]; }
        sT[j][0] = 1.f - t*(dy*dy + dz*dz);
        sT[j][1] = -s*dz + t*dx*dy;
        sT[j][2] =  s*dy + t*dx*dz;
        sT[j][3] = rx;
        sT[j][4] =  s*dz + t*dx*dy;
        sT[j][5] = 1.f - t*(dx*dx + dz*dz);
        sT[j][6] = -s*dx + t*dy*dz;
        sT[j][7] = ry;
        sT[j][8] = -s*dy + t*dx*dz;
        sT[j][9] =  s*dx + t*dy*dz;
        sT[j][10]= 1.f - t*(dx*dx + dy*dy);
        sT[j][11]= rz;
    }
    __syncthreads();
    if (j < 24) {
        int path[12]; int d = 0; int cur = j;
        while (cur >= 0) { path[d++] = cur; cur = c_par[cur]; }
        float g[12];
        int r = path[d - 1];
#pragma unroll
        for (int m = 0; m < 12; ++m) g[m] = sT[r][m];
        for (int i = d - 2; i >= 0; --i) {
            int n = path[i];
            float h[12];
#pragma unroll
            for (int row = 0; row < 3; ++row) {
                float a0 = g[row*4+0], a1 = g[row*4+1], a2 = g[row*4+2], a3 = g[row*4+3];
                h[row*4+0] = a0*sT[n][0] + a1*sT[n][4] + a2*sT[n][8];
                h[row*4+1] = a0*sT[n][1] + a1*sT[n][5] + a2*sT[n][9];
                h[row*4+2] = a0*sT[n][2] + a1*sT[n][6] + a2*sT[n][10];
                h[row*4+3] = a0*sT[n][3] + a1*sT[n][7] + a2*sT[n][11] + a3;
            }
#pragma unroll
            for (int m = 0; m < 12; ++m) g[m] = h[m];
        }
        size_t jo = (size_t)OUT_JT + ((size_t)b * 24 + j) * 3;
        P.out[jo+0] = g[3]; P.out[jo+1] = g[7]; P.out[jo+2] = g[11];
        float jx = sJ[j][0], jy = sJ[j][1], jz = sJ[j][2];
        float Av[12];
        Av[0]=g[0]; Av[1]=g[1]; Av[2]=g[2];   Av[3] = g[3]  - (g[0]*jx + g[1]*jy + g[2]*jz);
        Av[4]=g[4]; Av[5]=g[5]; Av[6]=g[6];   Av[7] = g[7]  - (g[4]*jx + g[5]*jy + g[6]*jz);
        Av[8]=g[8]; Av[9]=g[9]; Av[10]=g[10]; Av[11]= g[11] - (g[8]*jx + g[9]*jy + g[10]*jz);
        float* Ab = P.ws + O_A + ((size_t)b * 24 + j) * 12;
#pragma unroll
        for (int m = 0; m < 12; ++m) Ab[m] = Av[m];
        u16* at = P.wsu + O_AT;
#pragma unroll
        for (int m = 0; m < 3; ++m)
#pragma unroll
            for (int n = 0; n < 4; ++n)
                at[(size_t)(b*3 + m) * 96 + j*4 + n] = f2bf(Av[m*4 + n]);
    }
}

// ========== D2: MFMA GEMM (verts) + foot planes (R9-proven) ==========
__global__ __launch_bounds__(256) void k_d3(Params P) {
    if (blockIdx.y < 12) {
        __shared__ float ltile[64][66];
        const u16* wt = P.wsu + O_WT;
        const u16* at = P.wsu + O_AT;
        int tid = threadIdx.x;
        int lane = tid & 63;
        int wave = tid >> 6;
        int row_in = lane & 15, quad = lane >> 4;
        int v0 = blockIdx.x * 64 + wave * 16;
        int c0 = blockIdx.y * 64;

        f32x4 acc0 = {0.f,0.f,0.f,0.f}, acc1 = acc0, acc2 = acc0, acc3 = acc0;
#pragma unroll
        for (int kc = 0; kc < 96; kc += 32) {
            bf16x8 a  = *(const bf16x8*)(wt + (size_t)(v0 + row_in) * 96 + kc + quad * 8);
            bf16x8 b0 = *(const bf16x8*)(at + (size_t)(c0 +  0 + row_in) * 96 + kc + quad * 8);
            bf16x8 b1 = *(const bf16x8*)(at + (size_t)(c0 + 16 + row_in) * 96 + kc + quad * 8);
            bf16x8 b2 = *(const bf16x8*)(at + (size_t)(c0 + 32 + row_in) * 96 + kc + quad * 8);
            bf16x8 b3 = *(const bf16x8*)(at + (size_t)(c0 + 48 + row_in) * 96 + kc + quad * 8);
            acc0 = __builtin_amdgcn_mfma_f32_16x16x32_bf16(a, b0, acc0, 0, 0, 0);
            acc1 = __builtin_amdgcn_mfma_f32_16x16x32_bf16(a, b1, acc1, 0, 0, 0);
            acc2 = __builtin_amdgcn_mfma_f32_16x16x32_bf16(a, b2, acc2, 0, 0, 0);
            acc3 = __builtin_amdgcn_mfma_f32_16x16x32_bf16(a, b3, acc3, 0, 0, 0);
        }
        int vbase = wave * 16 + quad * 4;
#pragma unroll
        for (int s = 0; s < 4; ++s) {
            f32x4 acc = (s == 0) ? acc0 : (s == 1) ? acc1 : (s == 2) ? acc2 : acc3;
#pragma unroll
            for (int r = 0; r < 4; ++r)
                ltile[vbase + r][s * 16 + row_in] = acc[r];
        }
        __syncthreads();
        int vblk = blockIdx.x * 64;
        int bstart = c0 / 3;
        int bend = (c0 + 63) / 3;
        for (int b = bstart; b <= bend; ++b) {
            if (tid < 192) {
                int vl = tid / 3, m = tid - 3 * (tid / 3);
                int cl = b * 3 + m - c0;
                int v = vblk + vl;
                if (cl >= 0 && cl < 64 && v < NV)
                    P.out[((size_t)b * NV + v) * 3 + m] = ltile[vl][cl] + P.transl[b * 3 + m];
            }
        }
        return;
    }
    // ---- planes ----
    for (int idx = blockIdx.x * 256 + threadIdx.x; idx < NB_ * 400; idx += 108 * 256) {
        int b = idx / 400;
        int rr = idx - 400 * b;              // plane*100 + p
        const float* w  = P.ws + O_PW + rr * 24;
        const float* Ab = P.ws + O_A + (size_t)b * 288;
        float T[12];
#pragma unroll
        for (int m = 0; m < 12; ++m) T[m] = 0.f;
#pragma unroll
        for (int j = 0; j < NJ; ++j) {
            float wj = w[j];
#pragma unroll
            for (int m = 0; m < 12; ++m) T[m] += wj * Ab[j * 12 + m];
        }
        int plane = rr / 100, p = rr - 100 * plane;
        const float* ip = (plane == 0) ? P.ip_bl : (plane == 1) ? P.ip_fl
                        : (plane == 2) ? P.ip_br : P.ip_fr;
        size_t io = ((size_t)b * NP + p) * 3;
        float vx = ip[io+0], vy = ip[io+1], vz = ip[io+2];
        float ox = T[0]*vx + T[1]*vy + T[2]*vz  + T[3]  + P.transl[b*3+0];
        float oy = T[4]*vx + T[5]*vy + T[6]*vz  + T[7]  + P.transl[b*3+1];
        float oz = T[8]*vx + T[9]*vy + T[10]*vz + T[11] + P.transl[b*3+2];
        size_t o = (size_t)OUT_PLN + (size_t)idx * 3;
        P.out[o+0] = ox; P.out[o+1] = oy; P.out[o+2] = oz;
    }
}

extern "C" void kernel_launch(void* const* d_in, const int* in_sizes, int n_in,
                              void* d_out, int out_size, void* d_ws, size_t ws_size,
                              hipStream_t stream) {
    Params P;
    P.vt     = (const float*)d_in[0];
    P.sd     = (const float*)d_in[1];
    P.jreg   = (const float*)d_in[2];
    P.lw     = (const float*)d_in[3];
    P.betas  = (const float*)d_in[4];
    P.bpwf   = (const float*)d_in[5];
    P.rback  = (const float*)d_in[6];
    P.rfront = (const float*)d_in[7];
    P.lback  = (const float*)d_in[8];
    P.lfront = (const float*)d_in[9];
    P.transl = (const float*)d_in[10];
    P.gor    = (const float*)d_in[11];
    P.ip_bl  = (const float*)d_in[12];
    P.ip_fl  = (const float*)d_in[13];
    P.ip_br  = (const float*)d_in[14];
    P.ip_fr  = (const float*)d_in[15];
    // d_in[16] = parents (hardcoded)
    P.ids_bl = (const int*)d_in[17];
    P.ids_br = (const int*)d_in[18];
    P.ids_fl = (const int*)d_in[19];
    P.ids_fr = (const int*)d_in[20];
    P.ws  = (float*)d_ws;
    P.wsu = (u16*)d_ws;
    P.out = (float*)d_out;

    k_dA<<<dim3(27 + NFL + NB_), 256, 0, stream>>>(P);
    k_d3<<<dim3(108, 13), 256, 0, stream>>>(P);
}

// Round 14
// 145.063 us; speedup vs baseline: 3.4898x; 1.4393x over previous
//
#include <hip/hip_runtime.h>
#include <stdint.h>

#define NV 6890
#define NJ 24
#define NB_ 256
#define NP 100
#define MP 6912          // GEMM M padded to 108*64

// out element offsets (fp32)
#define OUT_JT   5291520
#define OUT_PLN  5309952

// workspace float offsets
#define O_JP 0           // 24*8*3 = 576 J_shaped partials
#define O_A  576         // 256*24*12 = 73728 fp32 joint transforms
#define O_PW 74304       // 400*24 = 9600 pre-gathered plane weights
// workspace u16 offsets
#define O_WT 169984      // W~ bf16 [MP][96] (byte 339968, 16B aligned)
#define O_AT 833536      // A~ bf16 [768][96] (byte 1667072, 16B aligned)

typedef unsigned short u16;
typedef unsigned int u32;
typedef __attribute__((ext_vector_type(8))) short bf16x8;
typedef __attribute__((ext_vector_type(4))) float f32x4;

__device__ __forceinline__ u16 f2bf(float f) {
    u32 u = __float_as_uint(f);
    u += 0x7FFFu + ((u >> 16) & 1u);   // RNE
    return (u16)(u >> 16);
}

__constant__ int c_par[24] = {-1,0,0,0,1,2,3,4,5,6,7,8,9,9,9,12,13,14,16,17,18,19,20,21};

struct Params {
    const float *vt, *sd, *jreg, *lw, *betas, *bpwf, *rback, *rfront,
                *lback, *lfront, *transl, *gor, *ip_bl, *ip_fl, *ip_br, *ip_fr;
    const int *ids_bl, *ids_fl, *ids_br, *ids_fr;
    float* ws;
    u16* wsu;
    float* out;
};

// ================= D1: W~ build + J_shaped partials =========================
__global__ __launch_bounds__(256) void k_d1(Params P) {
    int bx = blockIdx.x, tid = threadIdx.x;
    if (bx < 27) {
        // W~: one vertex/thread, vs computed inline from contiguous rows
        int v = bx * 256 + tid;                 // < 6912
        u16 buf[96];
        if (v < NV) {
            float be[11];
#pragma unroll
            for (int l = 0; l < 11; ++l) be[l] = P.betas[l];
            const float* sr = P.sd + (size_t)v * 30;
            const float* vr = P.vt + (size_t)v * 3;
            float vs[3];
#pragma unroll
            for (int n = 0; n < 3; ++n) {
                float acc = vr[n];
#pragma unroll
                for (int l = 0; l < 10; ++l) acc += be[1 + l] * sr[n * 10 + l];
                vs[n] = acc * be[0];
            }
            const float* wr = P.lw + (size_t)v * 24;
#pragma unroll
            for (int j = 0; j < 24; ++j) {
                float w = wr[j];
                buf[j*4+0] = f2bf(w * vs[0]);
                buf[j*4+1] = f2bf(w * vs[1]);
                buf[j*4+2] = f2bf(w * vs[2]);
                buf[j*4+3] = f2bf(w);
            }
        } else {
#pragma unroll
            for (int m = 0; m < 96; ++m) buf[m] = 0;
        }
        uint4* dst = (uint4*)(P.wsu + O_WT + (size_t)v * 96);
        const uint4* src = (const uint4*)buf;
#pragma unroll
        for (int m = 0; m < 12; ++m) dst[m] = src[m];
        return;
    }
    // J_shaped partials: (j, slice) = 24 x 8 blocks, ~862 vertices each
    {
        int idx = bx - 27;                      // < 192
        int j = idx >> 3, sl = idx & 7;
        int i0 = sl * 862, i1 = (i0 + 862 < NV) ? i0 + 862 : NV;
        float b0 = P.betas[0];
        float be[10];
#pragma unroll
        for (int l = 0; l < 10; ++l) be[l] = P.betas[1 + l];
        float s0 = 0.f, s1 = 0.f, s2 = 0.f;
        for (int i = i0 + tid; i < i1; i += 256) {
            float w = P.jreg[(size_t)j * NV + i];
            const float* sr = P.sd + (size_t)i * 30;
            const float* vr = P.vt + (size_t)i * 3;
            float c0 = vr[0], c1 = vr[1], c2 = vr[2];
#pragma unroll
            for (int l = 0; l < 10; ++l) {
                c0 += be[l] * sr[l];
                c1 += be[l] * sr[10 + l];
                c2 += be[l] * sr[20 + l];
            }
            s0 += w * (c0 * b0); s1 += w * (c1 * b0); s2 += w * (c2 * b0);
        }
        __shared__ float r0[256], r1[256], r2[256];
        r0[tid] = s0; r1[tid] = s1; r2[tid] = s2;
        __syncthreads();
        for (int off = 128; off > 0; off >>= 1) {
            if (tid < off) { r0[tid] += r0[tid+off]; r1[tid] += r1[tid+off]; r2[tid] += r2[tid+off]; }
            __syncthreads();
        }
        if (tid == 0) {
            P.ws[O_JP + (j*8 + sl)*3 + 0] = r0[0];
            P.ws[O_JP + (j*8 + sl)*3 + 1] = r1[0];
            P.ws[O_JP + (j*8 + sl)*3 + 2] = r2[0];
        }
    }
}

// ================= D2: chain per batch + plane-weight pregather =============
__global__ __launch_bounds__(256) void k_d2(Params P) {
    int bx = blockIdx.x, tid = threadIdx.x;
    if (bx >= NB_) {
        int q = (bx - NB_) * 256 + tid;
        if (q < 9600) {
            int rr = q / 24, j = q - 24 * rr;   // rr = plane*100+p
            int plane = rr / 100, p = rr - 100 * plane;
            const int* ids = (plane == 0) ? P.ids_bl : (plane == 1) ? P.ids_fl
                           : (plane == 2) ? P.ids_br : P.ids_fr;
            P.ws[O_PW + q] = P.lw[(size_t)ids[p] * 24 + j];
        }
        return;
    }
    int b = bx;
    __shared__ float js[72];
    __shared__ float sT[24][12];
    __shared__ float sJ[24][3];
    if (tid < 72) {
        int j = tid / 3, cc = tid - 3 * j;
        float a = 0.f;
#pragma unroll
        for (int s = 0; s < 8; ++s) a += P.ws[O_JP + (j*8 + s)*3 + cc];
        js[tid] = a;
    }
    __syncthreads();
    int j = tid;
    if (j < 24) {
        float px, py, pz;
        const float* bp = P.bpwf;
        if (j == 0)      { px = P.gor[b*3];   py = P.gor[b*3+1];   pz = P.gor[b*3+2]; }
        else if (j <= 6) { int o = b*57 + 3*(j-1); px = bp[o]; py = bp[o+1]; pz = bp[o+2]; }
        else if (j == 7) { px = P.lback[b*3]; py = P.lback[b*3+1]; pz = P.lback[b*3+2]; }
        else if (j == 8) { px = P.rback[b*3]; py = P.rback[b*3+1]; pz = P.rback[b*3+2]; }
        else if (j == 9) { int o = b*57 + 18;     px = bp[o]; py = bp[o+1]; pz = bp[o+2]; }
        else if (j == 10){ px = P.lfront[b];  py = 0.f; pz = 0.f; }
        else if (j == 11){ px = P.rfront[b];  py = 0.f; pz = 0.f; }
        else             { int o = b*57 + 21 + 3*(j-12); px = bp[o]; py = bp[o+1]; pz = bp[o+2]; }
        float ax = px + 1e-8f, ay = py + 1e-8f, az = pz + 1e-8f;
        float ang = sqrtf(ax*ax + ay*ay + az*az);
        float inv = 1.0f / ang;
        float dx = px * inv, dy = py * inv, dz = pz * inv;
        float c = cosf(ang), s = sinf(ang), t = 1.0f - c;
        sJ[j][0] = js[j*3]; sJ[j][1] = js[j*3+1]; sJ[j][2] = js[j*3+2];
        int p = c_par[j];
        float rx = sJ[j][0], ry = sJ[j][1], rz = sJ[j][2];
        if (p >= 0) { rx -= js[p*3]; ry -= js[p*3+1]; rz -= js[p*3+2]; }
        sT[j][0] = 1.f - t*(dy*dy + dz*dz);
        sT[j][1] = -s*dz + t*dx*dy;
        sT[j][2] =  s*dy + t*dx*dz;
        sT[j][3] = rx;
        sT[j][4] =  s*dz + t*dx*dy;
        sT[j][5] = 1.f - t*(dx*dx + dz*dz);
        sT[j][6] = -s*dx + t*dy*dz;
        sT[j][7] = ry;
        sT[j][8] = -s*dy + t*dx*dz;
        sT[j][9] =  s*dx + t*dy*dz;
        sT[j][10]= 1.f - t*(dx*dx + dy*dy);
        sT[j][11]= rz;
    }
    __syncthreads();
    if (j < 24) {
        int path[12]; int d = 0; int cur = j;
        while (cur >= 0) { path[d++] = cur; cur = c_par[cur]; }
        float g[12];
        int r = path[d - 1];
#pragma unroll
        for (int m = 0; m < 12; ++m) g[m] = sT[r][m];
        for (int i = d - 2; i >= 0; --i) {
            int n = path[i];
            float h[12];
#pragma unroll
            for (int row = 0; row < 3; ++row) {
                float a0 = g[row*4+0], a1 = g[row*4+1], a2 = g[row*4+2], a3 = g[row*4+3];
                h[row*4+0] = a0*sT[n][0] + a1*sT[n][4] + a2*sT[n][8];
                h[row*4+1] = a0*sT[n][1] + a1*sT[n][5] + a2*sT[n][9];
                h[row*4+2] = a0*sT[n][2] + a1*sT[n][6] + a2*sT[n][10];
                h[row*4+3] = a0*sT[n][3] + a1*sT[n][7] + a2*sT[n][11] + a3;
            }
#pragma unroll
            for (int m = 0; m < 12; ++m) g[m] = h[m];
        }
        size_t jo = (size_t)OUT_JT + ((size_t)b * 24 + j) * 3;
        P.out[jo+0] = g[3]; P.out[jo+1] = g[7]; P.out[jo+2] = g[11];
        float jx = sJ[j][0], jy = sJ[j][1], jz = sJ[j][2];
        float Av[12];
        Av[0]=g[0]; Av[1]=g[1]; Av[2]=g[2];   Av[3] = g[3]  - (g[0]*jx + g[1]*jy + g[2]*jz);
        Av[4]=g[4]; Av[5]=g[5]; Av[6]=g[6];   Av[7] = g[7]  - (g[4]*jx + g[5]*jy + g[6]*jz);
        Av[8]=g[8]; Av[9]=g[9]; Av[10]=g[10]; Av[11]= g[11] - (g[8]*jx + g[9]*jy + g[10]*jz);
        float* Ab = P.ws + O_A + ((size_t)b * 24 + j) * 12;
#pragma unroll
        for (int m = 0; m < 12; ++m) Ab[m] = Av[m];
        u16* at = P.wsu + O_AT;
#pragma unroll
        for (int m = 0; m < 3; ++m)
#pragma unroll
            for (int n = 0; n < 4; ++n)
                at[(size_t)(b*3 + m) * 96 + j*4 + n] = f2bf(Av[m*4 + n]);
    }
}

// ================= D3: MFMA GEMM (verts) + foot planes ======================
// grid (108, 13). y<12: 64x64 tile of D = W~ (MPx96) @ A~^T (96x768),
// LDS-staged epilogue for contiguous stores. y==12: planes (pregathered w).
__global__ __launch_bounds__(256) void k_d3(Params P) {
    if (blockIdx.y < 12) {
        __shared__ float ltile[64][66];
        const u16* wt = P.wsu + O_WT;
        const u16* at = P.wsu + O_AT;
        int tid = threadIdx.x;
        int lane = tid & 63;
        int wave = tid >> 6;
        int row_in = lane & 15, quad = lane >> 4;
        int v0 = blockIdx.x * 64 + wave * 16;
        int c0 = blockIdx.y * 64;

        f32x4 acc0 = {0.f,0.f,0.f,0.f}, acc1 = acc0, acc2 = acc0, acc3 = acc0;
#pragma unroll
        for (int kc = 0; kc < 96; kc += 32) {
            bf16x8 a  = *(const bf16x8*)(wt + (size_t)(v0 + row_in) * 96 + kc + quad * 8);
            bf16x8 b0 = *(const bf16x8*)(at + (size_t)(c0 +  0 + row_in) * 96 + kc + quad * 8);
            bf16x8 b1 = *(const bf16x8*)(at + (size_t)(c0 + 16 + row_in) * 96 + kc + quad * 8);
            bf16x8 b2 = *(const bf16x8*)(at + (size_t)(c0 + 32 + row_in) * 96 + kc + quad * 8);
            bf16x8 b3 = *(const bf16x8*)(at + (size_t)(c0 + 48 + row_in) * 96 + kc + quad * 8);
            acc0 = __builtin_amdgcn_mfma_f32_16x16x32_bf16(a, b0, acc0, 0, 0, 0);
            acc1 = __builtin_amdgcn_mfma_f32_16x16x32_bf16(a, b1, acc1, 0, 0, 0);
            acc2 = __builtin_amdgcn_mfma_f32_16x16x32_bf16(a, b2, acc2, 0, 0, 0);
            acc3 = __builtin_amdgcn_mfma_f32_16x16x32_bf16(a, b3, acc3, 0, 0, 0);
        }
        int vbase = wave * 16 + quad * 4;
#pragma unroll
        for (int s = 0; s < 4; ++s) {
            f32x4 acc = (s == 0) ? acc0 : (s == 1) ? acc1 : (s == 2) ? acc2 : acc3;
#pragma unroll
            for (int r = 0; r < 4; ++r)
                ltile[vbase + r][s * 16 + row_in] = acc[r];
        }
        __syncthreads();
        int vblk = blockIdx.x * 64;
        int bstart = c0 / 3;
        int bend = (c0 + 63) / 3;
        for (int b = bstart; b <= bend; ++b) {
            if (tid < 192) {
                int vl = tid / 3, m = tid - 3 * (tid / 3);
                int cl = b * 3 + m - c0;
                int v = vblk + vl;
                if (cl >= 0 && cl < 64 && v < NV)
                    P.out[((size_t)b * NV + v) * 3 + m] = ltile[vl][cl] + P.transl[b * 3 + m];
            }
        }
        return;
    }
    // ---- planes ----
    for (int idx = blockIdx.x * 256 + threadIdx.x; idx < NB_ * 400; idx += 108 * 256) {
        int b = idx / 400;
        int rr = idx - 400 * b;              // plane*100 + p
        const float* w  = P.ws + O_PW + rr * 24;
        const float* Ab = P.ws + O_A + (size_t)b * 288;
        float T[12];
#pragma unroll
        for (int m = 0; m < 12; ++m) T[m] = 0.f;
#pragma unroll
        for (int j = 0; j < NJ; ++j) {
            float wj = w[j];
#pragma unroll
            for (int m = 0; m < 12; ++m) T[m] += wj * Ab[j * 12 + m];
        }
        int plane = rr / 100, p = rr - 100 * plane;
        const float* ip = (plane == 0) ? P.ip_bl : (plane == 1) ? P.ip_fl
                        : (plane == 2) ? P.ip_br : P.ip_fr;
        size_t io = ((size_t)b * NP + p) * 3;
        float vx = ip[io+0], vy = ip[io+1], vz = ip[io+2];
        float ox = T[0]*vx + T[1]*vy + T[2]*vz  + T[3]  + P.transl[b*3+0];
        float oy = T[4]*vx + T[5]*vy + T[6]*vz  + T[7]  + P.transl[b*3+1];
        float oz = T[8]*vx + T[9]*vy + T[10]*vz + T[11] + P.transl[b*3+2];
        size_t o = (size_t)OUT_PLN + (size_t)idx * 3;
        P.out[o+0] = ox; P.out[o+1] = oy; P.out[o+2] = oz;
    }
}

extern "C" void kernel_launch(void* const* d_in, const int* in_sizes, int n_in,
                              void* d_out, int out_size, void* d_ws, size_t ws_size,
                              hipStream_t stream) {
    Params P;
    P.vt     = (const float*)d_in[0];
    P.sd     = (const float*)d_in[1];
    P.jreg   = (const float*)d_in[2];
    P.lw     = (const float*)d_in[3];
    P.betas  = (const float*)d_in[4];
    P.bpwf   = (const float*)d_in[5];
    P.rback  = (const float*)d_in[6];
    P.rfront = (const float*)d_in[7];
    P.lback  = (const float*)d_in[8];
    P.lfront = (const float*)d_in[9];
    P.transl = (const float*)d_in[10];
    P.gor    = (const float*)d_in[11];
    P.ip_bl  = (const float*)d_in[12];
    P.ip_fl  = (const float*)d_in[13];
    P.ip_br  = (const float*)d_in[14];
    P.ip_fr  = (const float*)d_in[15];
    // d_in[16] = parents (hardcoded)
    P.ids_bl = (const int*)d_in[17];
    P.ids_br = (const int*)d_in[18];
    P.ids_fl = (const int*)d_in[19];
    P.ids_fr = (const int*)d_in[20];
    P.ws  = (float*)d_ws;
    P.wsu = (u16*)d_ws;
    P.out = (float*)d_out;

    k_d1<<<dim3(27 + 192), 256, 0, stream>>>(P);
    k_d2<<<dim3(NB_ + 38), 256, 0, stream>>>(P);
    k_d3<<<dim3(108, 13), 256, 0, stream>>>(P);
}